// Round 4
// baseline (3196.190 us; speedup 1.0000x reference)
//
#include <hip/hip_runtime.h>
#include <hip/hip_bf16.h>

typedef unsigned short u16;
typedef unsigned int u32;

#define HD 512
#define BATCH 128
#define TENC 512
#define WPAD 520   // LDS row stride in bf16 elems (even -> u32-aligned rows)

typedef float f32x4 __attribute__((ext_vector_type(4)));
typedef short s16x8 __attribute__((ext_vector_type(8)));

__device__ __forceinline__ u16 f2b(float f) {
    u32 u = __float_as_uint(f);
    u32 r = (u + 0x7FFFu + ((u >> 16) & 1u)) >> 16;   // RNE
    return (u16)r;
}
__device__ __forceinline__ float b2f(u16 h) {
    return __uint_as_float(((u32)h) << 16);
}
__device__ __forceinline__ float sigm(float z) { return 1.0f / (1.0f + __expf(-z)); }
__device__ __forceinline__ float tanh_f(float z) { return 1.0f - 2.0f / (__expf(2.0f * z) + 1.0f); }

__device__ __forceinline__ u32 cld(const u32* p) {
    return __hip_atomic_load(p, __ATOMIC_RELAXED, __HIP_MEMORY_SCOPE_AGENT);
}
__device__ __forceinline__ void cst(u32* p, u32 v) {
    __hip_atomic_store(p, v, __ATOMIC_RELAXED, __HIP_MEMORY_SCOPE_AGENT);
}
// tag bands: value = payload + band. band=2 (even step): f in (0.5,4).
// band=6 (odd step): f > 4. poison (negative) / zeros fail both.
__device__ __forceinline__ bool okband(u32 v, float lo, float hi) {
    float f = __uint_as_float(v);
    return (f > lo) && (f < hi);
}

// ---------------------------------------------------------------------------
// init: seed encoder handoff ring slot 0 with h0 + band(even)=2.0
// ---------------------------------------------------------------------------
__global__ void init_misc(const float* __restrict__ h0, u32* __restrict__ hbT) {
    int idx = blockIdx.x * 256 + threadIdx.x;      // 256 blocks x 256 = 65536
    if (idx < 65536) {
        int bg = idx >> 9, j = idx & 511;          // bg = global batch row
        int g = bg >> 4, bl = bg & 15;
        hbT[(size_t)g * 8192 + bl * 512 + j] = __float_as_uint(h0[idx] + 2.0f);
    }
}

// ---------------------------------------------------------------------------
// Encoder LSTM: 8 batch-groups x 16 wgs. Whh register-resident. Cross-wg h
// handoff: tagged f32 (h+band) relaxed write-through stores; readers poll the
// data itself (ring depth 3, parity band). No flags, no waitcnt, no fences.
// ---------------------------------------------------------------------------
__global__ __launch_bounds__(512, 2) void enc_lstm(
    const float* __restrict__ xseq, const float* __restrict__ c0,
    const float* __restrict__ Wih, const float* __restrict__ Whh,
    const float* __restrict__ bih, const float* __restrict__ bhh,
    u16* __restrict__ enc, u32* __restrict__ hbT) {

    __shared__ u16 hlds[16 * WPAD];     // staged h tile [16 b][512 k] bf16
    __shared__ float exg[16 * 132];     // gate pre-activations [b][128 rows]
    __shared__ float bias_l[128];
    __shared__ float wih_l[128];

    const int tid = threadIdx.x;
    const int g = blockIdx.x & 7;       // batch group
    const int sl = blockIdx.x >> 3;     // hidden slot 0..15

    if (tid < 128) {
        int n = (tid >> 5) * 512 + sl * 32 + (tid & 31);
        bias_l[tid] = bih[n] + bhh[n];
        wih_l[tid] = Wih[n];
    }

    const int bT = tid >> 5, jl = tid & 31;               // cell-update mapping
    float c = c0[(g * 16 + bT) * HD + sl * 32 + jl];      // persistent cell state

    const int lane = tid & 63, wv = tid >> 6;
    const int q = lane >> 4, cl = lane & 15;
    const int R = (wv >> 1) * 32 + (wv & 1) * 16;         // wave's 16 gate-rows

    // this lane's 16 B-fragments of Whh in registers (64 VGPRs)
    s16x8 bw[16];
    {
        int r = R + cl;
        int grow = (r >> 5) * 512 + sl * 32 + (r & 31);
        const float* wrow = Whh + (size_t)grow * 512;
        #pragma unroll
        for (int ks = 0; ks < 16; ++ks) {
            s16x8 v;
            #pragma unroll
            for (int j = 0; j < 8; ++j)
                v[j] = (short)f2b(wrow[ks * 32 + q * 8 + j]);
            bw[ks] = v;
        }
    }
    __syncthreads();

    for (int t = 0; t < TENC; ++t) {
        // ---- stage h_t: poll tagged data, 16 coalesced words per thread
        const u32* src = hbT + (size_t)((t % 3) * 8 + g) * 8192;
        const float lo = (t & 1) ? 4.0f : 0.5f;
        const float hi = (t & 1) ? 3e38f : 4.0f;
        const float band = (t & 1) ? 6.0f : 2.0f;
        u32 v[16];
        #pragma unroll
        for (int i = 0; i < 16; ++i) v[i] = cld(src + i * 512 + tid);
        #pragma unroll
        for (int i = 0; i < 16; ++i) {
            while (!okband(v[i], lo, hi)) {
                __builtin_amdgcn_s_sleep(1);
                v[i] = cld(src + i * 512 + tid);
            }
            hlds[i * WPAD + tid] = f2b(__uint_as_float(v[i]) - band);
        }
        float xv = xseq[t * BATCH + g * 16 + bT];
        __syncthreads();

        // ---- MFMA: gates[b][R+cl] over K=512
        f32x4 acc = {0.f, 0.f, 0.f, 0.f};
        #pragma unroll
        for (int ks = 0; ks < 16; ++ks) {
            s16x8 av = *(const s16x8*)&hlds[cl * WPAD + ks * 32 + q * 8];
            acc = __builtin_amdgcn_mfma_f32_16x16x32_bf16(av, bw[ks], acc, 0, 0, 0);
        }
        #pragma unroll
        for (int r4 = 0; r4 < 4; ++r4)
            exg[(q * 4 + r4) * 132 + R + cl] = acc[r4];   // row m = batch, col n
        __syncthreads();

        // ---- LSTM cell for (bT, jl)
        const float* exb = &exg[bT * 132];
        float gi = exb[jl]      + xv * wih_l[jl]      + bias_l[jl];
        float gf = exb[32 + jl] + xv * wih_l[32 + jl] + bias_l[32 + jl];
        float gg = exb[64 + jl] + xv * wih_l[64 + jl] + bias_l[64 + jl];
        float go = exb[96 + jl] + xv * wih_l[96 + jl] + bias_l[96 + jl];
        c = sigm(gf) * c + sigm(gi) * tanh_f(gg);
        float hv = sigm(go) * tanh_f(c);
        int jgl = sl * 32 + jl;

        // tagged handoff store (fire and forget) + enc bf16 store
        float bw2 = ((t + 1) & 1) ? 6.0f : 2.0f;
        cst(hbT + (size_t)(((t + 1) % 3) * 8 + g) * 8192 + bT * 512 + jgl,
            __float_as_uint(hv + bw2));
        enc[((size_t)t * BATCH + g * 16 + bT) * HD + jgl] = f2b(hv);
    }
}

// ---------------------------------------------------------------------------
// Fused decoder, one dispatch, 132 wgs:
//   wg 0..3   : RNN wgs — rWhh bf16 register-resident (128 j-rows each).
//               stage h_s (tagged ring) -> MFMA (overlaps att p2) -> poll x_s
//               -> tanh -> store h_{s+1} tagged.
//   wg 4..131 : attention wg per batch row b — poll h_{s+1}, online-softmax
//               attention over 512 enc rows (8-t batched), project, store
//               out_s (dout + tagged x-buffer).
// ---------------------------------------------------------------------------
__global__ __launch_bounds__(512, 2) void dec_all(
    const float* __restrict__ xlast, const u16* __restrict__ enc,
    const float* __restrict__ rWhh, const float* __restrict__ rWih,
    const float* __restrict__ rbih, const float* __restrict__ rbhh,
    const float* __restrict__ linW, const float* __restrict__ linb,
    float* __restrict__ dout, u32* __restrict__ hh, u32* __restrict__ xb) {

    __shared__ union {
        struct {
            u16 hlds[128 * WPAD];      // 133120 B: h_s bf16 [128 b][512 k]
            float xl[128];
            float wihl[128];
            float biasl[128];
        } r;
        struct {
            float hn[512];
            float ctxl[8 * 512];
            float red[512];
            float mw[8], lw[8];
        } a;
    } sm;

    const int tid = threadIdx.x;
    const int wg = blockIdx.x;
    const int lane = tid & 63, wv = tid >> 6;

    if (wg < 4) {
        // ================= RNN workgroup =================
        const int q = lane >> 4, cl = lane & 15;
        const int R = (wv >> 1) * 32 + (wv & 1) * 16;     // 16 j-rows per wave
        const int jbase = wg * 128;

        if (tid < 128) {
            sm.r.wihl[tid] = rWih[jbase + tid];
            sm.r.biasl[tid] = rbih[jbase + tid] + rbhh[jbase + tid];
        }
        // register-resident rWhh fragments: rows jbase+R+cl, 512 k
        s16x8 bw[16];
        {
            const float* wrow = rWhh + (size_t)(jbase + R + cl) * 512;
            #pragma unroll
            for (int ks = 0; ks < 16; ++ks) {
                s16x8 v;
                #pragma unroll
                for (int j = 0; j < 8; ++j)
                    v[j] = (short)f2b(wrow[ks * 32 + q * 8 + j]);
                bw[ks] = v;
            }
        }
        __syncthreads();

        for (int s = 0; s < 32; ++s) {
            // ---- stage h_s into LDS bf16 [128 b][512 k]
            if (s == 0) {
                const u16* h0p = enc + (size_t)511 * BATCH * HD;
                for (int b = 0; b < 128; ++b)
                    sm.r.hlds[b * WPAD + tid] = h0p[b * HD + tid];
            } else {
                const u32* src = hh + (size_t)(s % 3) * 65536;
                const float lo = (s & 1) ? 4.0f : 0.5f;
                const float hi = (s & 1) ? 3e38f : 4.0f;
                const float band = (s & 1) ? 6.0f : 2.0f;
                for (int blk = 0; blk < 4; ++blk) {
                    u32 v[32];
                    #pragma unroll
                    for (int i = 0; i < 32; ++i)
                        v[i] = cld(src + (blk * 32 + i) * 512 + tid);
                    #pragma unroll
                    for (int i = 0; i < 32; ++i) {
                        while (!okband(v[i], lo, hi)) {
                            __builtin_amdgcn_s_sleep(1);
                            v[i] = cld(src + (blk * 32 + i) * 512 + tid);
                        }
                        sm.r.hlds[(blk * 32 + i) * WPAD + tid] =
                            f2b(__uint_as_float(v[i]) - band);
                    }
                }
            }
            __syncthreads();

            // ---- GEMM: a[b][j] = h_s @ Whh^T  (overlaps att step s-1)
            f32x4 acc[8];
            #pragma unroll
            for (int mt = 0; mt < 8; ++mt) acc[mt] = (f32x4){0.f, 0.f, 0.f, 0.f};
            #pragma unroll
            for (int ks = 0; ks < 16; ++ks) {
                s16x8 bv = bw[ks];
                #pragma unroll
                for (int mt = 0; mt < 8; ++mt) {
                    s16x8 av = *(const s16x8*)
                        &sm.r.hlds[(mt * 16 + cl) * WPAD + ks * 32 + q * 8];
                    acc[mt] = __builtin_amdgcn_mfma_f32_16x16x32_bf16(av, bv, acc[mt], 0, 0, 0);
                }
            }

            // ---- poll x_s (arrives after att step s-1 completes)
            if (s == 0) {
                if (tid < 128) sm.r.xl[tid] = xlast[tid];
            } else {
                if (tid < 128) {
                    u32 v = cld(xb + s * 128 + tid);
                    while (!okband(v, 0.5f, 3e38f)) {
                        __builtin_amdgcn_s_sleep(1);
                        v = cld(xb + s * 128 + tid);
                    }
                    sm.r.xl[tid] = __uint_as_float(v) - 2.0f;
                }
            }
            __syncthreads();

            // ---- h_{s+1} = tanh(a + x*wih + bias), tagged store to ring
            const int m1 = s + 1;
            u32* dst = hh + (size_t)(m1 % 3) * 65536;
            const float bandw = (m1 & 1) ? 6.0f : 2.0f;
            const int jloc = R + cl;
            const float wihj = sm.r.wihl[jloc];
            const float biaj = sm.r.biasl[jloc];
            #pragma unroll
            for (int mt = 0; mt < 8; ++mt) {
                #pragma unroll
                for (int r4 = 0; r4 < 4; ++r4) {
                    int b = mt * 16 + q * 4 + r4;
                    float val = acc[mt][r4] + sm.r.xl[b] * wihj + biaj;
                    float hvv = tanh_f(val);
                    cst(dst + b * 512 + jbase + jloc, __float_as_uint(hvv + bandw));
                }
            }
            __syncthreads();   // guard hlds/xl reuse vs next iteration
        }
    } else {
        // ================= attention workgroup (one batch row) =================
        const int b = wg - 4;
        const float lwt = linW[tid];
        const float lb = linb[0];
        const u16* eb = enc + (size_t)b * HD + lane * 8;  // t-stride = 65536 elems

        for (int s = 0; s < 32; ++s) {
            // issue first enc prefetch block before polling h (hides latency)
            uint4 ev[8];
            #pragma unroll
            for (int i = 0; i < 8; ++i)
                ev[i] = *(const uint4*)(eb + (size_t)(wv + 8 * i) * 65536);

            // ---- poll h_{s+1}
            {
                const int m1 = s + 1;
                const u32* src = hh + (size_t)(m1 % 3) * 65536 + b * 512;
                const float lo = (m1 & 1) ? 4.0f : 0.5f;
                const float hi = (m1 & 1) ? 3e38f : 4.0f;
                const float band = (m1 & 1) ? 6.0f : 2.0f;
                u32 v = cld(src + tid);
                while (!okband(v, lo, hi)) {
                    __builtin_amdgcn_s_sleep(1);
                    v = cld(src + tid);
                }
                sm.a.hn[tid] = __uint_as_float(v) - band;
            }
            __syncthreads();

            float h8[8];
            #pragma unroll
            for (int i = 0; i < 8; ++i) h8[i] = sm.a.hn[lane * 8 + i];

            // ---- online-softmax attention, 8 t's per iteration
            float m = -1e30f, l = 0.f;
            float acc[8] = {0, 0, 0, 0, 0, 0, 0, 0};
            for (int blk = 0; blk < 8; ++blk) {
                uint4 nx[8];
                if (blk < 7) {
                    #pragma unroll
                    for (int i = 0; i < 8; ++i)
                        nx[i] = *(const uint4*)(eb +
                                 (size_t)(wv + 8 * ((blk + 1) * 8 + i)) * 65536);
                }
                float sp[8];
                #pragma unroll
                for (int i = 0; i < 8; ++i) {
                    uint4 e4 = ev[i];
                    float d = 0.f;
                    d = fmaf(b2f((u16)(e4.x & 0xFFFF)), h8[0], d);
                    d = fmaf(b2f((u16)(e4.x >> 16)),    h8[1], d);
                    d = fmaf(b2f((u16)(e4.y & 0xFFFF)), h8[2], d);
                    d = fmaf(b2f((u16)(e4.y >> 16)),    h8[3], d);
                    d = fmaf(b2f((u16)(e4.z & 0xFFFF)), h8[4], d);
                    d = fmaf(b2f((u16)(e4.z >> 16)),    h8[5], d);
                    d = fmaf(b2f((u16)(e4.w & 0xFFFF)), h8[6], d);
                    d = fmaf(b2f((u16)(e4.w >> 16)),    h8[7], d);
                    sp[i] = d;
                }
                #pragma unroll
                for (int mk = 1; mk < 64; mk <<= 1) {
                    #pragma unroll
                    for (int i = 0; i < 8; ++i) sp[i] += __shfl_xor(sp[i], mk, 64);
                }
                float bm = sp[0];
                #pragma unroll
                for (int i = 1; i < 8; ++i) bm = fmaxf(bm, sp[i]);
                float nm = fmaxf(m, bm);
                float sc = __expf(m - nm);
                l *= sc;
                #pragma unroll
                for (int j = 0; j < 8; ++j) acc[j] *= sc;
                #pragma unroll
                for (int i = 0; i < 8; ++i) {
                    float p = __expf(sp[i] - nm);
                    l += p;
                    uint4 e4 = ev[i];
                    acc[0] = fmaf(p, b2f((u16)(e4.x & 0xFFFF)), acc[0]);
                    acc[1] = fmaf(p, b2f((u16)(e4.x >> 16)),    acc[1]);
                    acc[2] = fmaf(p, b2f((u16)(e4.y & 0xFFFF)), acc[2]);
                    acc[3] = fmaf(p, b2f((u16)(e4.y >> 16)),    acc[3]);
                    acc[4] = fmaf(p, b2f((u16)(e4.z & 0xFFFF)), acc[4]);
                    acc[5] = fmaf(p, b2f((u16)(e4.z >> 16)),    acc[5]);
                    acc[6] = fmaf(p, b2f((u16)(e4.w & 0xFFFF)), acc[6]);
                    acc[7] = fmaf(p, b2f((u16)(e4.w >> 16)),    acc[7]);
                }
                m = nm;
                #pragma unroll
                for (int i = 0; i < 8; ++i) ev[i] = nx[i];
            }
            if (lane == 0) { sm.a.mw[wv] = m; sm.a.lw[wv] = l; }
            #pragma unroll
            for (int i = 0; i < 8; ++i) sm.a.ctxl[wv * HD + lane * 8 + i] = acc[i];
            __syncthreads();

            // ---- merge 8 waves' states, project, relu, emit
            float M = sm.a.mw[0];
            #pragma unroll
            for (int i = 1; i < 8; ++i) M = fmaxf(M, sm.a.mw[i]);
            float L = 0.f, aw[8];
            #pragma unroll
            for (int i = 0; i < 8; ++i) {
                aw[i] = __expf(sm.a.mw[i] - M);
                L += aw[i] * sm.a.lw[i];
            }
            float cj = 0.f;
            #pragma unroll
            for (int i = 0; i < 8; ++i) cj = fmaf(aw[i], sm.a.ctxl[i * HD + tid], cj);
            float r = cj * lwt;
            #pragma unroll
            for (int mk = 1; mk < 64; mk <<= 1) r += __shfl_xor(r, mk, 64);
            if (lane == 0) sm.a.red[wv] = r;
            __syncthreads();
            if (tid == 0) {
                float o = (sm.a.red[0] + sm.a.red[1] + sm.a.red[2] + sm.a.red[3] +
                           sm.a.red[4] + sm.a.red[5] + sm.a.red[6] + sm.a.red[7]) / L + lb;
                o = fmaxf(o, 0.f);
                dout[s * BATCH + b] = o;
                if (s < 31)
                    cst(xb + (s + 1) * 128 + b, __float_as_uint(o + 2.0f));
            }
            __syncthreads();   // guard hn/ctxl reuse vs next iteration
        }
    }
}

// ---------------------------------------------------------------------------
extern "C" void kernel_launch(void* const* d_in, const int* in_sizes, int n_in,
                              void* d_out, int out_size, void* d_ws, size_t ws_size,
                              hipStream_t stream) {
    const float* xseq = (const float*)d_in[0];   // [513,128,1]
    const float* h0   = (const float*)d_in[1];
    const float* c0   = (const float*)d_in[2];
    const float* Wih  = (const float*)d_in[3];   // [2048,1]
    const float* Whh  = (const float*)d_in[4];   // [2048,512]
    const float* bih  = (const float*)d_in[5];
    const float* bhh  = (const float*)d_in[6];
    const float* rWih = (const float*)d_in[7];   // [512,1]
    const float* rWhh = (const float*)d_in[8];   // [512,512]
    const float* rbih = (const float*)d_in[9];
    const float* rbhh = (const float*)d_in[10];
    const float* linW = (const float*)d_in[11];  // [1,512]
    const float* linb = (const float*)d_in[12];
    float* dout = (float*)d_out;                 // [32,128,1]

    // workspace layout (~65.6 MB)
    char* ws = (char*)d_ws;
    u16* enc = (u16*)ws;                                   // 64 MB
    u32* hbT = (u32*)(ws + 67108864);                      // enc handoff ring: 3x8x8192 f32
    u32* hh  = (u32*)(ws + 67108864 + 786432);             // dec h ring: 3x65536 f32
    u32* xb  = (u32*)(ws + 67108864 + 786432 + 786432);    // dec x: 32x128 f32

    init_misc<<<256, 256, 0, stream>>>(h0, hbT);
    enc_lstm<<<128, 512, 0, stream>>>(xseq, c0, Wih, Whh, bih, bhh, enc, hbT);
    dec_all<<<132, 512, 0, stream>>>(xseq + 512 * BATCH, enc, rWhh, rWih,
                                     rbih, rbhh, linW, linb, dout, hh, xb);
}